// Round 1
// baseline (1564.994 us; speedup 1.0000x reference)
//
#include <hip/hip_runtime.h>

typedef _Float16 half_t;
typedef _Float16 half2_t __attribute__((ext_vector_type(2)));
typedef _Float16 half8_t __attribute__((ext_vector_type(8)));
typedef float float4_t __attribute__((ext_vector_type(4)));

// Problem constants
#define BB 64
#define TT 512
#define EE 128
#define HPP 128
#define KK 32
#define G4 512           // 4*HP
#define MTOT (BB*TT)     // 32768
#define NWID 1024        // stacked fwd(512)+bwd(512) gate rows

// ---------------------------------------------------------------- lengths
__global__ void k_lengths(const int* __restrict__ x, int* __restrict__ lens) {
    __shared__ int cnt;
    if (threadIdx.x == 0) cnt = 0;
    __syncthreads();
    int local = 0;
    for (int t = threadIdx.x; t < TT; t += blockDim.x)
        local += (x[blockIdx.x * TT + t] > 0) ? 1 : 0;
    atomicAdd(&cnt, local);
    __syncthreads();
    if (threadIdx.x == 0) lens[blockIdx.x] = cnt;
}

// ---------------------------------------------------------------- pack weights fp32->fp16, stacked [fwd;bwd] in [N,K] layout
__global__ void k_pack(const float* __restrict__ wi0f, const float* __restrict__ wi0b,
                       const float* __restrict__ wi1f, const float* __restrict__ wi1b,
                       half_t* __restrict__ W0, half_t* __restrict__ W1) {
    int idx = blockIdx.x * blockDim.x + threadIdx.x;
    int stride = gridDim.x * blockDim.x;
    const int n0 = NWID * EE;       // 1024*128
    const int n1 = NWID * 256;      // 1024*256
    for (int i = idx; i < n0; i += stride) {
        int r = i >> 7, c = i & 127;
        float v = (r < 512) ? wi0f[r * 128 + c] : wi0b[(r - 512) * 128 + c];
        W0[i] = (half_t)v;
    }
    for (int i = idx; i < n1; i += stride) {
        int r = i >> 8, c = i & 255;
        float v = (r < 512) ? wi1f[r * 256 + c] : wi1b[(r - 512) * 256 + c];
        W1[i] = (half_t)v;
    }
}

// ---------------------------------------------------------------- embedding gather -> fp16
__global__ void k_embed(const int* __restrict__ x, const float* __restrict__ embed,
                        half_t* __restrict__ e16) {
    int bt = blockIdx.x * 16 + (threadIdx.x >> 4);
    int c  = (threadIdx.x & 15) * 8;
    int xi = x[bt];
    const float4* src = (const float4*)(embed + (size_t)xi * EE + c);
    float4 a = src[0], b = src[1];
    half8_t o;
    o[0] = (half_t)a.x; o[1] = (half_t)a.y; o[2] = (half_t)a.z; o[3] = (half_t)a.w;
    o[4] = (half_t)b.x; o[5] = (half_t)b.y; o[6] = (half_t)b.z; o[7] = (half_t)b.w;
    *(half8_t*)(e16 + (size_t)bt * EE + c) = o;
}

// ---------------------------------------------------------------- MFMA GEMM: C[M,1024] = A[M,Kd] * W[1024,Kd]^T + bias
// block 256 thr (4 waves); wave w: m-strip 16 rows, 256 n-cols (16 tiles of 16x16x32 MFMA)
__global__ __launch_bounds__(256) void k_gemm(const half_t* __restrict__ A,
                                              const half_t* __restrict__ W,
                                              const float* __restrict__ bias_f,
                                              const float* __restrict__ bias_b,
                                              half_t* __restrict__ C, int Kd) {
    int wave = threadIdx.x >> 6;
    int lane = threadIdx.x & 63;
    int m0 = blockIdx.x * 64 + wave * 16;
    int n0 = blockIdx.y * 256;
    int lr = lane & 15;     // A: m-row | W: n-row | D: col
    int lq = lane >> 4;     // k-quad (k offset = lq*8) | D: row-quad

    float4_t acc[16];
    #pragma unroll
    for (int i = 0; i < 16; i++) acc[i] = (float4_t){0.f, 0.f, 0.f, 0.f};

    const half_t* Arow = A + (size_t)(m0 + lr) * Kd + lq * 8;
    const half_t* Wrow = W + (size_t)(n0 + lr) * Kd + lq * 8;

    for (int k = 0; k < Kd; k += 32) {
        half8_t af = *(const half8_t*)(Arow + k);
        #pragma unroll
        for (int nt = 0; nt < 16; nt++) {
            half8_t bf = *(const half8_t*)(Wrow + (size_t)nt * 16 * Kd + k);
            acc[nt] = __builtin_amdgcn_mfma_f32_16x16x32_f16(af, bf, acc[nt], 0, 0, 0);
        }
    }
    #pragma unroll
    for (int nt = 0; nt < 16; nt++) {
        int n = n0 + nt * 16 + lr;
        float bias = (n < 512) ? bias_f[n] : bias_b[n - 512];
        #pragma unroll
        for (int i = 0; i < 4; i++) {
            int m = m0 + lq * 4 + i;
            C[(size_t)m * NWID + n] = (half_t)(acc[nt][i] + bias);
        }
    }
}

// ---------------------------------------------------------------- recurrent LSTM phase (one block per (seq,dir))
// 512 thr: tid = rg*4 + kq ; thread owns rows {rg + g*128} g=0..3 (all gates of cell rg), k-range [kq*32, kq*32+32)
__global__ __launch_bounds__(512) void k_lstm(const half_t* __restrict__ zbuf,
                                              const float* __restrict__ wh_f,
                                              const float* __restrict__ wh_b,
                                              const int* __restrict__ lens,
                                              half_t* __restrict__ hout) {
    int b   = blockIdx.x >> 1;
    int dir = blockIdx.x & 1;
    int tid = threadIdx.x;
    int kq  = tid & 3;
    int rg  = tid >> 2;
    const float* wh = dir ? wh_b : wh_f;
    int Lb = lens[b];

    __shared__ __align__(16) half_t hbuf[2][HPP];

    // weights -> fp16 VGPRs: 4 rows x 32 k = 64 half2
    half2_t w[4][16];
    #pragma unroll
    for (int g = 0; g < 4; g++) {
        const float* src = wh + (size_t)(rg + g * 128) * 128 + kq * 32;
        #pragma unroll
        for (int j = 0; j < 16; j++) {
            half2_t t;
            t[0] = (half_t)src[2 * j];
            t[1] = (half_t)src[2 * j + 1];
            w[g][j] = t;
        }
    }
    if (tid < HPP) { hbuf[0][tid] = (half_t)0.f; hbuf[1][tid] = (half_t)0.f; }
    float c = 0.f;
    const half_t* zbase = zbuf + dir * 512;
    half_t* hbase = hout + dir * 128;
    __syncthreads();

    for (int t = 0; t < Lb; t++) {
        int time = dir ? (Lb - 1 - t) : t;
        size_t row = (size_t)(b * TT + time);
        const half_t* zin = zbase + row * NWID;
        // issue z_in loads early (all threads; only kq==0 consumes) to hide L2 latency
        float zv0 = (float)zin[rg];
        float zv1 = (float)zin[rg + 128];
        float zv2 = (float)zin[rg + 256];
        float zv3 = (float)zin[rg + 384];

        int rb = t & 1;
        half8_t hv[4];
        #pragma unroll
        for (int j = 0; j < 4; j++)
            hv[j] = *(const half8_t*)&hbuf[rb][kq * 32 + j * 8];
        const half2_t* hreg = (const half2_t*)hv;

        float p0 = 0.f, p1 = 0.f, p2 = 0.f, p3 = 0.f;
        #pragma unroll
        for (int j = 0; j < 16; j++) {
            p0 = __builtin_amdgcn_fdot2(w[0][j], hreg[j], p0, false);
            p1 = __builtin_amdgcn_fdot2(w[1][j], hreg[j], p1, false);
            p2 = __builtin_amdgcn_fdot2(w[2][j], hreg[j], p2, false);
            p3 = __builtin_amdgcn_fdot2(w[3][j], hreg[j], p3, false);
        }
        p0 += __shfl_xor(p0, 1); p0 += __shfl_xor(p0, 2);
        p1 += __shfl_xor(p1, 1); p1 += __shfl_xor(p1, 2);
        p2 += __shfl_xor(p2, 1); p2 += __shfl_xor(p2, 2);
        p3 += __shfl_xor(p3, 1); p3 += __shfl_xor(p3, 2);

        if (kq == 0) {
            float zi = p0 + zv0;
            float zf = p1 + zv1;
            float zg = p2 + zv2;
            float zo = p3 + zv3;
            float si = 1.f / (1.f + __expf(-zi));
            float sf = 1.f / (1.f + __expf(-zf));
            float so = 1.f / (1.f + __expf(-zo));
            float tg = 1.f - 2.f / (__expf(2.f * zg) + 1.f);
            c = sf * c + si * tg;
            float th = 1.f - 2.f / (__expf(2.f * c) + 1.f);
            float h = so * th;
            hbuf[rb ^ 1][rg] = (half_t)h;
            hbase[row * 256 + rg] = (half_t)h;
        }
        __syncthreads();
    }
}

// ---------------------------------------------------------------- output projection: logits[bt,k] = h1[bt,:256] . w_out[k,:] + b_out[k]
__global__ __launch_bounds__(256) void k_logits(const half_t* __restrict__ h1,
                                                const float* __restrict__ w_out,
                                                const float* __restrict__ b_out,
                                                float* __restrict__ logits) {
    int bt = blockIdx.x * 8 + (threadIdx.x >> 5);
    int k  = threadIdx.x & 31;
    const half2_t* h = (const half2_t*)(h1 + (size_t)bt * 256);
    const float2*  w = (const float2*)(w_out + (size_t)k * 256);
    float s = b_out[k];
    #pragma unroll 8
    for (int d = 0; d < 128; d++) {
        half2_t hv = h[d];
        float2  wv = w[d];
        s += (float)hv[0] * wv.x + (float)hv[1] * wv.y;
    }
    logits[(size_t)bt * KK + k] = s;
}

// ---------------------------------------------------------------- CRF forward + gold score (one wave per sequence)
__global__ __launch_bounds__(64) void k_crf(const float* __restrict__ logits,
                                            const float* __restrict__ trans,
                                            const int* __restrict__ y,
                                            const int* __restrict__ lens,
                                            float* __restrict__ out) {
    int b = blockIdx.x;
    int lane = threadIdx.x;
    __shared__ float ET[32][33];   // exp(trans), padded vs bank conflicts
    __shared__ float TR[32][33];
    __shared__ float PS[32];

    for (int i = lane; i < 1024; i += 64) {
        int k = i >> 5, j = i & 31;
        float tv = trans[i];
        TR[k][j] = tv;
        ET[k][j] = __expf(tv);     // exp(-10000) underflows to exact 0
    }
    __syncthreads();

    int Lb = lens[b];
    const int* yb = y + b * (TT + 1);

    // ---- gold score (parallel over t)
    float g = 0.f;
    for (int t = lane; t < Lb; t += 64) {
        int yt = yb[t], yt1 = yb[t + 1];
        g += logits[((size_t)(b * TT + t)) * KK + yt1] + TR[yt1][yt];
    }
    #pragma unroll
    for (int s = 1; s < 64; s <<= 1) g += __shfl_xor(g, s);
    float gold = g + TR[3][yb[Lb]];   // + trans[EOS, last_tag]

    // ---- CRF forward recursion. lane: tag k = lane&31, half hh = lane>>5 handles 16 j's
    int k  = lane & 31;
    int hh = lane >> 5;
    float score = (k == 2) ? 0.f : -10000.f;   // SOS = 2
    const float* lgbase = logits + (size_t)(b * TT) * KK;

    for (int t = 0; t < Lb; t++) {
        float lg = lgbase[t * KK + k];   // prefetch; consumed at end of iter
        float m = score;
        #pragma unroll
        for (int s = 1; s < 32; s <<= 1) m = fmaxf(m, __shfl_xor(m, s));
        float P = __expf(score - m);
        if (hh == 0) PS[k] = P;
        __syncthreads();
        float acc = 0.f;
        #pragma unroll
        for (int i2 = 0; i2 < 16; i2++)
            acc += ET[k][hh * 16 + i2] * PS[hh * 16 + i2];
        acc += __shfl_xor(acc, 32);
        __syncthreads();
        score = lg + m + __logf(acc);   // log(0) = -inf is benign (dead tag)
    }

    // logZ = LSE_k(score[k] + trans[EOS,k])
    float v = score + TR[3][k];
    float m2 = v;
    #pragma unroll
    for (int s = 1; s < 32; s <<= 1) m2 = fmaxf(m2, __shfl_xor(m2, s));
    float e = __expf(v - m2);
    #pragma unroll
    for (int s = 1; s < 32; s <<= 1) e += __shfl_xor(e, s);
    float logZ = m2 + __logf(e);

    if (lane == 0) out[b] = logZ - gold;
}

// ----------------------------------------------------------------
extern "C" void kernel_launch(void* const* d_in, const int* in_sizes, int n_in,
                              void* d_out, int out_size, void* d_ws, size_t ws_size,
                              hipStream_t stream) {
    const int*   x      = (const int*)d_in[0];
    const int*   y      = (const int*)d_in[1];
    const float* embed  = (const float*)d_in[2];
    const float* wi_l0f = (const float*)d_in[3];
    const float* wh_l0f = (const float*)d_in[4];
    const float* b_l0f  = (const float*)d_in[5];
    const float* wi_l0b = (const float*)d_in[6];
    const float* wh_l0b = (const float*)d_in[7];
    const float* b_l0b  = (const float*)d_in[8];
    const float* wi_l1f = (const float*)d_in[9];
    const float* wh_l1f = (const float*)d_in[10];
    const float* b_l1f  = (const float*)d_in[11];
    const float* wi_l1b = (const float*)d_in[12];
    const float* wh_l1b = (const float*)d_in[13];
    const float* b_l1b  = (const float*)d_in[14];
    const float* w_out  = (const float*)d_in[15];
    const float* b_out  = (const float*)d_in[16];
    const float* trans  = (const float*)d_in[17];
    float* out = (float*)d_out;

    char* base = (char*)d_ws;
    size_t off = 0;
    auto take = [&](size_t bytes) -> char* {
        char* r = base + off;
        off = (off + bytes + 255) & ~(size_t)255;
        return r;
    };
    half_t* zA  = (half_t*)take((size_t)MTOT * NWID * 2);  // 64 MiB (reused layer0/layer1)
    half_t* h0  = (half_t*)take((size_t)MTOT * 256 * 2);   // 16 MiB
    half_t* h1  = (half_t*)take((size_t)MTOT * 256 * 2);   // 16 MiB
    half_t* e16 = (half_t*)take((size_t)MTOT * EE * 2);    // 8 MiB
    float*  lg  = (float*)take((size_t)MTOT * KK * 4);     // 4 MiB
    half_t* W0  = (half_t*)take((size_t)NWID * EE * 2);
    half_t* W1  = (half_t*)take((size_t)NWID * 256 * 2);
    int*    lens = (int*)take(BB * 4);

    k_lengths<<<BB, 256, 0, stream>>>(x, lens);
    k_pack<<<256, 256, 0, stream>>>(wi_l0f, wi_l0b, wi_l1f, wi_l1b, W0, W1);
    k_embed<<<MTOT / 16, 256, 0, stream>>>(x, embed, e16);
    k_gemm<<<dim3(MTOT / 64, 4), 256, 0, stream>>>(e16, W0, b_l0f, b_l0b, zA, 128);
    k_lstm<<<BB * 2, 512, 0, stream>>>(zA, wh_l0f, wh_l0b, lens, h0);
    k_gemm<<<dim3(MTOT / 64, 4), 256, 0, stream>>>(h0, W1, b_l1f, b_l1b, zA, 256);
    k_lstm<<<BB * 2, 512, 0, stream>>>(zA, wh_l1f, wh_l1b, lens, h1);
    k_logits<<<MTOT / 8, 256, 0, stream>>>(h1, w_out, b_out, lg);
    k_crf<<<BB, 64, 0, stream>>>(lg, trans, y, lens, out);
}

// Round 2
// 1444.164 us; speedup vs baseline: 1.0837x; 1.0837x over previous
//
#include <hip/hip_runtime.h>

typedef _Float16 half_t;
typedef _Float16 half2_t __attribute__((ext_vector_type(2)));
typedef _Float16 half8_t __attribute__((ext_vector_type(8)));
typedef float float4_t __attribute__((ext_vector_type(4)));

// Problem constants
#define BB 64
#define TT 512
#define EE 128
#define HPP 128
#define KK 32
#define MTOT (BB*TT)     // 32768
#define NWID 1024        // stacked fwd(512)+bwd(512) gate rows

// full-rate in-quad butterfly adds via DPP quad_perm (lanes tid=rg*4+kq -> quad == the 4 kq chunks)
__device__ __forceinline__ float dpp_xor1_add(float x) {
    int y = __builtin_amdgcn_update_dpp(0, __builtin_bit_cast(int, x), 0xB1, 0xF, 0xF, true); // [1,0,3,2]
    return x + __builtin_bit_cast(float, y);
}
__device__ __forceinline__ float dpp_xor2_add(float x) {
    int y = __builtin_amdgcn_update_dpp(0, __builtin_bit_cast(int, x), 0x4E, 0xF, 0xF, true); // [2,3,0,1]
    return x + __builtin_bit_cast(float, y);
}

// barrier that drains ONLY LDS ops: lets z-prefetch loads + h stores stay in flight (no vmcnt(0) drain)
__device__ __forceinline__ void lds_barrier() {
    asm volatile("s_waitcnt lgkmcnt(0)\n\ts_barrier" ::: "memory");
}

// ---------------------------------------------------------------- lengths
__global__ void k_lengths(const int* __restrict__ x, int* __restrict__ lens) {
    __shared__ int cnt;
    if (threadIdx.x == 0) cnt = 0;
    __syncthreads();
    int local = 0;
    for (int t = threadIdx.x; t < TT; t += blockDim.x)
        local += (x[blockIdx.x * TT + t] > 0) ? 1 : 0;
    atomicAdd(&cnt, local);
    __syncthreads();
    if (threadIdx.x == 0) lens[blockIdx.x] = cnt;
}

// ---------------------------------------------------------------- pack weights fp32->fp16, stacked [fwd;bwd] in [N,K] layout
__global__ void k_pack(const float* __restrict__ wi0f, const float* __restrict__ wi0b,
                       const float* __restrict__ wi1f, const float* __restrict__ wi1b,
                       half_t* __restrict__ W0, half_t* __restrict__ W1) {
    int idx = blockIdx.x * blockDim.x + threadIdx.x;
    int stride = gridDim.x * blockDim.x;
    const int n0 = NWID * EE;       // 1024*128
    const int n1 = NWID * 256;      // 1024*256
    for (int i = idx; i < n0; i += stride) {
        int r = i >> 7, c = i & 127;
        float v = (r < 512) ? wi0f[r * 128 + c] : wi0b[(r - 512) * 128 + c];
        W0[i] = (half_t)v;
    }
    for (int i = idx; i < n1; i += stride) {
        int r = i >> 8, c = i & 255;
        float v = (r < 512) ? wi1f[r * 256 + c] : wi1b[(r - 512) * 256 + c];
        W1[i] = (half_t)v;
    }
}

// ---------------------------------------------------------------- embedding gather -> fp16
__global__ void k_embed(const int* __restrict__ x, const float* __restrict__ embed,
                        half_t* __restrict__ e16) {
    int bt = blockIdx.x * 16 + (threadIdx.x >> 4);
    int c  = (threadIdx.x & 15) * 8;
    int xi = x[bt];
    const float4* src = (const float4*)(embed + (size_t)xi * EE + c);
    float4 a = src[0], b = src[1];
    half8_t o;
    o[0] = (half_t)a.x; o[1] = (half_t)a.y; o[2] = (half_t)a.z; o[3] = (half_t)a.w;
    o[4] = (half_t)b.x; o[5] = (half_t)b.y; o[6] = (half_t)b.z; o[7] = (half_t)b.w;
    *(half8_t*)(e16 + (size_t)bt * EE + c) = o;
}

// ---------------------------------------------------------------- MFMA GEMM: C[M,1024] = A[M,Kd] * W[1024,Kd]^T + bias
__global__ __launch_bounds__(256) void k_gemm(const half_t* __restrict__ A,
                                              const half_t* __restrict__ W,
                                              const float* __restrict__ bias_f,
                                              const float* __restrict__ bias_b,
                                              half_t* __restrict__ C, int Kd) {
    int wave = threadIdx.x >> 6;
    int lane = threadIdx.x & 63;
    int m0 = blockIdx.x * 64 + wave * 16;
    int n0 = blockIdx.y * 256;
    int lr = lane & 15;     // A: m-row | W: n-row | D: col
    int lq = lane >> 4;     // k-quad (k offset = lq*8) | D: row-quad

    float4_t acc[16];
    #pragma unroll
    for (int i = 0; i < 16; i++) acc[i] = (float4_t){0.f, 0.f, 0.f, 0.f};

    const half_t* Arow = A + (size_t)(m0 + lr) * Kd + lq * 8;
    const half_t* Wrow = W + (size_t)(n0 + lr) * Kd + lq * 8;

    for (int k = 0; k < Kd; k += 32) {
        half8_t af = *(const half8_t*)(Arow + k);
        #pragma unroll
        for (int nt = 0; nt < 16; nt++) {
            half8_t bf = *(const half8_t*)(Wrow + (size_t)nt * 16 * Kd + k);
            acc[nt] = __builtin_amdgcn_mfma_f32_16x16x32_f16(af, bf, acc[nt], 0, 0, 0);
        }
    }
    #pragma unroll
    for (int nt = 0; nt < 16; nt++) {
        int n = n0 + nt * 16 + lr;
        float bias = (n < 512) ? bias_f[n] : bias_b[n - 512];
        #pragma unroll
        for (int i = 0; i < 4; i++) {
            int m = m0 + lq * 4 + i;
            C[(size_t)m * NWID + n] = (half_t)(acc[nt][i] + bias);
        }
    }
}

// ---------------------------------------------------------------- recurrent LSTM phase (one block per (seq,dir))
// 512 thr: tid = rg*4 + kq ; thread owns rows {rg + g*128} g=0..3 (all gates of cell rg), k-range [kq*32, kq*32+32)
// R2: z software-pipelined one step ahead; DPP quad reduce; lgkm-only barrier.
__global__ __launch_bounds__(512) void k_lstm(const half_t* __restrict__ zbuf,
                                              const float* __restrict__ wh_f,
                                              const float* __restrict__ wh_b,
                                              const int* __restrict__ lens,
                                              half_t* __restrict__ hout) {
    int b   = blockIdx.x >> 1;
    int dir = blockIdx.x & 1;
    int tid = threadIdx.x;
    int kq  = tid & 3;
    int rg  = tid >> 2;
    const float* wh = dir ? wh_b : wh_f;
    int Lb = lens[b];

    __shared__ __align__(16) half_t hbuf[2][HPP];

    // weights -> fp16 VGPRs/AGPRs: 4 rows x 32 k = 64 half2
    half2_t w[4][16];
    #pragma unroll
    for (int g = 0; g < 4; g++) {
        const float* src = wh + (size_t)(rg + g * 128) * 128 + kq * 32;
        #pragma unroll
        for (int j = 0; j < 16; j++) {
            half2_t t;
            t[0] = (half_t)src[2 * j];
            t[1] = (half_t)src[2 * j + 1];
            w[g][j] = t;
        }
    }
    if (tid < HPP) { hbuf[0][tid] = (half_t)0.f; hbuf[1][tid] = (half_t)0.f; }
    float c = 0.f;
    const half_t* zbase = zbuf + dir * 512;
    half_t* hbase = hout + dir * 128;

    // prologue: prefetch z(0)
    int time0 = dir ? (Lb - 1) : 0;
    const half_t* zin0 = zbase + (size_t)(b * TT + time0) * NWID;
    float zv0 = (float)zin0[rg];
    float zv1 = (float)zin0[rg + 128];
    float zv2 = (float)zin0[rg + 256];
    float zv3 = (float)zin0[rg + 384];

    __syncthreads();

    for (int t = 0; t < Lb; t++) {
        int time = dir ? (Lb - 1 - t) : t;
        size_t row = (size_t)(b * TT + time);

        int rb = t & 1;
        half8_t hv[4];
        #pragma unroll
        for (int j = 0; j < 4; j++)
            hv[j] = *(const half8_t*)&hbuf[rb][kq * 32 + j * 8];
        const half2_t* hreg = (const half2_t*)hv;

        float p0 = 0.f, p1 = 0.f, p2 = 0.f, p3 = 0.f;
        #pragma unroll
        for (int j = 0; j < 16; j++) {
            p0 = __builtin_amdgcn_fdot2(w[0][j], hreg[j], p0, false);
            p1 = __builtin_amdgcn_fdot2(w[1][j], hreg[j], p1, false);
            p2 = __builtin_amdgcn_fdot2(w[2][j], hreg[j], p2, false);
            p3 = __builtin_amdgcn_fdot2(w[3][j], hreg[j], p3, false);
        }
        // in-quad butterfly: full-rate DPP, all lanes get totals
        p0 = dpp_xor2_add(dpp_xor1_add(p0));
        p1 = dpp_xor2_add(dpp_xor1_add(p1));
        p2 = dpp_xor2_add(dpp_xor1_add(p2));
        p3 = dpp_xor2_add(dpp_xor1_add(p3));

        // prefetch z(t+1) — consumed next iteration (latency hidden by act + barrier + dot)
        int tn = (t + 1 < Lb) ? (t + 1) : t;
        int timen = dir ? (Lb - 1 - tn) : tn;
        const half_t* zinn = zbase + (size_t)(b * TT + timen) * NWID;
        float nz0 = (float)zinn[rg];
        float nz1 = (float)zinn[rg + 128];
        float nz2 = (float)zinn[rg + 256];
        float nz3 = (float)zinn[rg + 384];

        if (kq == 0) {
            float zi = p0 + zv0;
            float zf = p1 + zv1;
            float zg = p2 + zv2;
            float zo = p3 + zv3;
            float si = 1.f / (1.f + __expf(-zi));
            float sf = 1.f / (1.f + __expf(-zf));
            float so = 1.f / (1.f + __expf(-zo));
            float tg = 1.f - 2.f / (__expf(2.f * zg) + 1.f);
            c = sf * c + si * tg;
            float th = 1.f - 2.f / (__expf(2.f * c) + 1.f);
            float h = so * th;
            hbuf[rb ^ 1][rg] = (half_t)h;
            hbase[row * 256 + rg] = (half_t)h;   // fire-and-forget (not drained at barrier)
        }
        zv0 = nz0; zv1 = nz1; zv2 = nz2; zv3 = nz3;

        lds_barrier();   // lgkmcnt(0) only — z loads + h stores stay in flight
    }
}

// ---------------------------------------------------------------- output projection
__global__ __launch_bounds__(256) void k_logits(const half_t* __restrict__ h1,
                                                const float* __restrict__ w_out,
                                                const float* __restrict__ b_out,
                                                float* __restrict__ logits) {
    int bt = blockIdx.x * 8 + (threadIdx.x >> 5);
    int k  = threadIdx.x & 31;
    const half2_t* h = (const half2_t*)(h1 + (size_t)bt * 256);
    const float2*  w = (const float2*)(w_out + (size_t)k * 256);
    float s = b_out[k];
    #pragma unroll 8
    for (int d = 0; d < 128; d++) {
        half2_t hv = h[d];
        float2  wv = w[d];
        s += (float)hv[0] * wv.x + (float)hv[1] * wv.y;
    }
    logits[(size_t)bt * KK + k] = s;
}

// ---------------------------------------------------------------- CRF forward + gold score (one wave per sequence)
__global__ __launch_bounds__(64) void k_crf(const float* __restrict__ logits,
                                            const float* __restrict__ trans,
                                            const int* __restrict__ y,
                                            const int* __restrict__ lens,
                                            float* __restrict__ out) {
    int b = blockIdx.x;
    int lane = threadIdx.x;
    __shared__ float ET[32][33];   // exp(trans), padded vs bank conflicts
    __shared__ float TR[32][33];
    __shared__ float PS[32];

    for (int i = lane; i < 1024; i += 64) {
        int k = i >> 5, j = i & 31;
        float tv = trans[i];
        TR[k][j] = tv;
        ET[k][j] = __expf(tv);     // exp(-10000) underflows to exact 0
    }
    __syncthreads();

    int Lb = lens[b];
    const int* yb = y + b * (TT + 1);

    // ---- gold score (parallel over t)
    float g = 0.f;
    for (int t = lane; t < Lb; t += 64) {
        int yt = yb[t], yt1 = yb[t + 1];
        g += logits[((size_t)(b * TT + t)) * KK + yt1] + TR[yt1][yt];
    }
    #pragma unroll
    for (int s = 1; s < 64; s <<= 1) g += __shfl_xor(g, s);
    float gold = g + TR[3][yb[Lb]];   // + trans[EOS, last_tag]

    // ---- CRF forward recursion. lane: tag k = lane&31, half hh = lane>>5 handles 16 j's
    int k  = lane & 31;
    int hh = lane >> 5;
    float score = (k == 2) ? 0.f : -10000.f;   // SOS = 2
    const float* lgbase = logits + (size_t)(b * TT) * KK;

    for (int t = 0; t < Lb; t++) {
        float lg = lgbase[t * KK + k];
        float m = score;
        #pragma unroll
        for (int s = 1; s < 32; s <<= 1) m = fmaxf(m, __shfl_xor(m, s));
        float P = __expf(score - m);
        if (hh == 0) PS[k] = P;
        __syncthreads();
        float acc = 0.f;
        #pragma unroll
        for (int i2 = 0; i2 < 16; i2++)
            acc += ET[k][hh * 16 + i2] * PS[hh * 16 + i2];
        acc += __shfl_xor(acc, 32);
        __syncthreads();
        score = lg + m + __logf(acc);
    }

    float v = score + TR[3][k];
    float m2 = v;
    #pragma unroll
    for (int s = 1; s < 32; s <<= 1) m2 = fmaxf(m2, __shfl_xor(m2, s));
    float e = __expf(v - m2);
    #pragma unroll
    for (int s = 1; s < 32; s <<= 1) e += __shfl_xor(e, s);
    float logZ = m2 + __logf(e);

    if (lane == 0) out[b] = logZ - gold;
}

// ----------------------------------------------------------------
extern "C" void kernel_launch(void* const* d_in, const int* in_sizes, int n_in,
                              void* d_out, int out_size, void* d_ws, size_t ws_size,
                              hipStream_t stream) {
    const int*   x      = (const int*)d_in[0];
    const int*   y      = (const int*)d_in[1];
    const float* embed  = (const float*)d_in[2];
    const float* wi_l0f = (const float*)d_in[3];
    const float* wh_l0f = (const float*)d_in[4];
    const float* b_l0f  = (const float*)d_in[5];
    const float* wi_l0b = (const float*)d_in[6];
    const float* wh_l0b = (const float*)d_in[7];
    const float* b_l0b  = (const float*)d_in[8];
    const float* wi_l1f = (const float*)d_in[9];
    const float* wh_l1f = (const float*)d_in[10];
    const float* b_l1f  = (const float*)d_in[11];
    const float* wi_l1b = (const float*)d_in[12];
    const float* wh_l1b = (const float*)d_in[13];
    const float* b_l1b  = (const float*)d_in[14];
    const float* w_out  = (const float*)d_in[15];
    const float* b_out  = (const float*)d_in[16];
    const float* trans  = (const float*)d_in[17];
    float* out = (float*)d_out;

    char* base = (char*)d_ws;
    size_t off = 0;
    auto take = [&](size_t bytes) -> char* {
        char* r = base + off;
        off = (off + bytes + 255) & ~(size_t)255;
        return r;
    };
    half_t* zA  = (half_t*)take((size_t)MTOT * NWID * 2);  // 64 MiB (reused layer0/layer1)
    half_t* h0  = (half_t*)take((size_t)MTOT * 256 * 2);   // 16 MiB
    half_t* h1  = (half_t*)take((size_t)MTOT * 256 * 2);   // 16 MiB
    half_t* e16 = (half_t*)take((size_t)MTOT * EE * 2);    // 8 MiB
    float*  lg  = (float*)take((size_t)MTOT * KK * 4);     // 4 MiB
    half_t* W0  = (half_t*)take((size_t)NWID * EE * 2);
    half_t* W1  = (half_t*)take((size_t)NWID * 256 * 2);
    int*    lens = (int*)take(BB * 4);

    k_lengths<<<BB, 256, 0, stream>>>(x, lens);
    k_pack<<<256, 256, 0, stream>>>(wi_l0f, wi_l0b, wi_l1f, wi_l1b, W0, W1);
    k_embed<<<MTOT / 16, 256, 0, stream>>>(x, embed, e16);
    k_gemm<<<dim3(MTOT / 64, 4), 256, 0, stream>>>(e16, W0, b_l0f, b_l0b, zA, 128);
    k_lstm<<<BB * 2, 512, 0, stream>>>(zA, wh_l0f, wh_l0b, lens, h0);
    k_gemm<<<dim3(MTOT / 64, 4), 256, 0, stream>>>(h0, W1, b_l1f, b_l1b, zA, 256);
    k_lstm<<<BB * 2, 512, 0, stream>>>(zA, wh_l1f, wh_l1b, lens, h1);
    k_logits<<<MTOT / 8, 256, 0, stream>>>(h1, w_out, b_out, lg);
    k_crf<<<BB, 64, 0, stream>>>(lg, trans, y, lens, out);
}

// Round 3
// 1297.123 us; speedup vs baseline: 1.2065x; 1.1134x over previous
//
#include <hip/hip_runtime.h>

typedef _Float16 half_t;
typedef _Float16 half2_t __attribute__((ext_vector_type(2)));
typedef _Float16 half4_t __attribute__((ext_vector_type(4)));
typedef _Float16 half8_t __attribute__((ext_vector_type(8)));
typedef float float4_t __attribute__((ext_vector_type(4)));

// Problem constants
#define BB 64
#define TT 512
#define EE 128
#define HPP 128
#define KK 32
#define MTOT (BB*TT)     // 32768
#define NWID 1024        // stacked fwd(512)+bwd(512) gate rows

// full-rate in-quad butterfly adds via DPP quad_perm (lanes tid=rg*4+kq)
__device__ __forceinline__ float dpp_xor1_add(float x) {
    int y = __builtin_amdgcn_update_dpp(0, __builtin_bit_cast(int, x), 0xB1, 0xF, 0xF, true); // [1,0,3,2]
    return x + __builtin_bit_cast(float, y);
}
__device__ __forceinline__ float dpp_xor2_add(float x) {
    int y = __builtin_amdgcn_update_dpp(0, __builtin_bit_cast(int, x), 0x4E, 0xF, 0xF, true); // [2,3,0,1]
    return x + __builtin_bit_cast(float, y);
}

// barrier that drains ONLY LDS ops (no vmcnt(0) drain: z prefetch + h stores stay in flight)
__device__ __forceinline__ void lds_barrier() {
    asm volatile("s_waitcnt lgkmcnt(0)\n\ts_barrier" ::: "memory");
}

// ---------------------------------------------------------------- lengths
__global__ void k_lengths(const int* __restrict__ x, int* __restrict__ lens) {
    __shared__ int cnt;
    if (threadIdx.x == 0) cnt = 0;
    __syncthreads();
    int local = 0;
    for (int t = threadIdx.x; t < TT; t += blockDim.x)
        local += (x[blockIdx.x * TT + t] > 0) ? 1 : 0;
    atomicAdd(&cnt, local);
    __syncthreads();
    if (threadIdx.x == 0) lens[blockIdx.x] = cnt;
}

// ---------------------------------------------------------------- pack weights fp32->fp16 (wi stacked [fwd;bwd], [N,K]; w_out [32,256])
__global__ void k_pack(const float* __restrict__ wi0f, const float* __restrict__ wi0b,
                       const float* __restrict__ wi1f, const float* __restrict__ wi1b,
                       const float* __restrict__ w_out,
                       half_t* __restrict__ W0, half_t* __restrict__ W1,
                       half_t* __restrict__ WO) {
    int idx = blockIdx.x * blockDim.x + threadIdx.x;
    int stride = gridDim.x * blockDim.x;
    const int n0 = NWID * EE;       // 1024*128
    const int n1 = NWID * 256;      // 1024*256
    for (int i = idx; i < n0; i += stride) {
        int r = i >> 7, c = i & 127;
        float v = (r < 512) ? wi0f[r * 128 + c] : wi0b[(r - 512) * 128 + c];
        W0[i] = (half_t)v;
    }
    for (int i = idx; i < n1; i += stride) {
        int r = i >> 8, c = i & 255;
        float v = (r < 512) ? wi1f[r * 256 + c] : wi1b[(r - 512) * 256 + c];
        W1[i] = (half_t)v;
    }
    for (int i = idx; i < KK * 256; i += stride)
        WO[i] = (half_t)w_out[i];
}

// ---------------------------------------------------------------- embedding gather -> fp16
__global__ void k_embed(const int* __restrict__ x, const float* __restrict__ embed,
                        half_t* __restrict__ e16) {
    int bt = blockIdx.x * 16 + (threadIdx.x >> 4);
    int c  = (threadIdx.x & 15) * 8;
    int xi = x[bt];
    const float4* src = (const float4*)(embed + (size_t)xi * EE + c);
    float4 a = src[0], b = src[1];
    half8_t o;
    o[0] = (half_t)a.x; o[1] = (half_t)a.y; o[2] = (half_t)a.z; o[3] = (half_t)a.w;
    o[4] = (half_t)b.x; o[5] = (half_t)b.y; o[6] = (half_t)b.z; o[7] = (half_t)b.w;
    *(half8_t*)(e16 + (size_t)bt * EE + c) = o;
}

// ---------------------------------------------------------------- MFMA GEMM: C[M,1024] = A[M,Kd]*W[1024,Kd]^T + bias
// epilogue permutes n -> gate-interleaved: within each dir-half, np = cell*4 + gate
__global__ __launch_bounds__(256) void k_gemm(const half_t* __restrict__ A,
                                              const half_t* __restrict__ W,
                                              const float* __restrict__ bias_f,
                                              const float* __restrict__ bias_b,
                                              half_t* __restrict__ C, int Kd) {
    int wave = threadIdx.x >> 6;
    int lane = threadIdx.x & 63;
    int m0 = blockIdx.x * 64 + wave * 16;
    int n0 = blockIdx.y * 256;
    int lr = lane & 15;
    int lq = lane >> 4;

    float4_t acc[16];
    #pragma unroll
    for (int i = 0; i < 16; i++) acc[i] = (float4_t){0.f, 0.f, 0.f, 0.f};

    const half_t* Arow = A + (size_t)(m0 + lr) * Kd + lq * 8;
    const half_t* Wrow = W + (size_t)(n0 + lr) * Kd + lq * 8;

    for (int k = 0; k < Kd; k += 32) {
        half8_t af = *(const half8_t*)(Arow + k);
        #pragma unroll
        for (int nt = 0; nt < 16; nt++) {
            half8_t bf = *(const half8_t*)(Wrow + (size_t)nt * 16 * Kd + k);
            acc[nt] = __builtin_amdgcn_mfma_f32_16x16x32_f16(af, bf, acc[nt], 0, 0, 0);
        }
    }
    #pragma unroll
    for (int nt = 0; nt < 16; nt++) {
        int n = n0 + nt * 16 + lr;
        int n2 = (n < 512) ? n : n - 512;
        float bias = (n < 512) ? bias_f[n2] : bias_b[n2];
        int np = ((n < 512) ? 0 : 512) + (n2 & 127) * 4 + (n2 >> 7);
        #pragma unroll
        for (int i = 0; i < 4; i++) {
            int m = m0 + lq * 4 + i;
            C[(size_t)m * NWID + np] = (half_t)(acc[nt][i] + bias);
        }
    }
}

// ---------------------------------------------------------------- recurrent LSTM phase (one block per (seq,dir))
// 512 thr: tid = rg*4 + kq ; thread owns rows {rg + g*128} g=0..3, k-range [kq*32, kq*32+32)
// R3: launch_bounds(512,2) -> weights in arch VGPRs; z gate-interleaved half4 on kq==0 only; depth-2 prefetch.
__global__ __launch_bounds__(512, 2) void k_lstm(const half_t* __restrict__ zbuf,
                                                 const float* __restrict__ wh_f,
                                                 const float* __restrict__ wh_b,
                                                 const int* __restrict__ lens,
                                                 half_t* __restrict__ hout) {
    int b   = blockIdx.x >> 1;
    int dir = blockIdx.x & 1;
    int tid = threadIdx.x;
    int kq  = tid & 3;
    int rg  = tid >> 2;
    const float* wh = dir ? wh_b : wh_f;
    int Lb = lens[b];

    __shared__ __align__(16) half_t hbuf[2][HPP];

    // weights -> fp16 VGPRs: 4 rows x 32 k = 64 half2
    half2_t w[4][16];
    #pragma unroll
    for (int g = 0; g < 4; g++) {
        const float* src = wh + (size_t)(rg + g * 128) * 128 + kq * 32;
        #pragma unroll
        for (int j = 0; j < 16; j++) {
            half2_t t;
            t[0] = (half_t)src[2 * j];
            t[1] = (half_t)src[2 * j + 1];
            w[g][j] = t;
        }
    }
    if (tid < HPP) { hbuf[0][tid] = (half_t)0.f; hbuf[1][tid] = (half_t)0.f; }
    float c = 0.f;
    const half_t* zcol = zbuf + dir * 512;   // gate-interleaved: + row*NWID + rg*4
    half_t* hbase = hout + dir * 128;

    // depth-2 prefetch ring (kq==0 lanes only)
    half4_t z1 = (half4_t){0, 0, 0, 0}, z2 = (half4_t){0, 0, 0, 0};
    if (kq == 0) {
        int t0 = dir ? (Lb - 1) : 0;
        int t1 = dir ? (Lb - 2) : 1;     // Lb >= 256, safe
        z1 = *(const half4_t*)(zcol + (size_t)(b * TT + t0) * NWID + rg * 4);
        z2 = *(const half4_t*)(zcol + (size_t)(b * TT + t1) * NWID + rg * 4);
    }
    __syncthreads();

    for (int t = 0; t < Lb; t++) {
        int time = dir ? (Lb - 1 - t) : t;
        size_t row = (size_t)(b * TT + time);

        int rb = t & 1;
        half8_t hv[4];
        #pragma unroll
        for (int j = 0; j < 4; j++)
            hv[j] = *(const half8_t*)&hbuf[rb][kq * 32 + j * 8];
        const half2_t* hreg = (const half2_t*)hv;

        float p0 = 0.f, p1 = 0.f, p2 = 0.f, p3 = 0.f;
        #pragma unroll
        for (int j = 0; j < 16; j++) {
            p0 = __builtin_amdgcn_fdot2(w[0][j], hreg[j], p0, false);
            p1 = __builtin_amdgcn_fdot2(w[1][j], hreg[j], p1, false);
            p2 = __builtin_amdgcn_fdot2(w[2][j], hreg[j], p2, false);
            p3 = __builtin_amdgcn_fdot2(w[3][j], hreg[j], p3, false);
        }
        p0 = dpp_xor2_add(dpp_xor1_add(p0));
        p1 = dpp_xor2_add(dpp_xor1_add(p1));
        p2 = dpp_xor2_add(dpp_xor1_add(p2));
        p3 = dpp_xor2_add(dpp_xor1_add(p3));

        // prefetch z(t+2)
        half4_t znew = z2;
        if (kq == 0) {
            int tn = (t + 2 < Lb) ? (t + 2) : (Lb - 1);
            int timen = dir ? (Lb - 1 - tn) : tn;
            znew = *(const half4_t*)(zcol + (size_t)(b * TT + timen) * NWID + rg * 4);
        }

        if (kq == 0) {
            float zi = p0 + (float)z1[0];
            float zf = p1 + (float)z1[1];
            float zg = p2 + (float)z1[2];
            float zo = p3 + (float)z1[3];
            float si = 1.f / (1.f + __expf(-zi));
            float sf = 1.f / (1.f + __expf(-zf));
            float so = 1.f / (1.f + __expf(-zo));
            float tg = 1.f - 2.f / (__expf(2.f * zg) + 1.f);
            c = sf * c + si * tg;
            float th = 1.f - 2.f / (__expf(2.f * c) + 1.f);
            float h = so * th;
            hbuf[rb ^ 1][rg] = (half_t)h;
            hbase[row * 256 + rg] = (half_t)h;   // fire-and-forget
        }
        z1 = z2; z2 = znew;

        lds_barrier();   // lgkmcnt(0) only
    }
}

// ---------------------------------------------------------------- output projection via MFMA: logits[bt,32] = h1[bt,:256] . WO[k,:]^T + b_out
__global__ __launch_bounds__(256) void k_logits(const half_t* __restrict__ h1,
                                                const half_t* __restrict__ WO,
                                                const float* __restrict__ b_out,
                                                float* __restrict__ logits) {
    int wave = threadIdx.x >> 6;
    int lane = threadIdx.x & 63;
    int m0 = blockIdx.x * 64 + wave * 16;
    int lr = lane & 15;
    int lq = lane >> 4;

    float4_t acc[2];
    acc[0] = (float4_t){0.f, 0.f, 0.f, 0.f};
    acc[1] = (float4_t){0.f, 0.f, 0.f, 0.f};

    const half_t* Arow = h1 + (size_t)(m0 + lr) * 256 + lq * 8;
    const half_t* Brow = WO + (size_t)lr * 256 + lq * 8;

    #pragma unroll
    for (int k = 0; k < 256; k += 32) {
        half8_t af = *(const half8_t*)(Arow + k);
        half8_t b0 = *(const half8_t*)(Brow + k);
        half8_t b1 = *(const half8_t*)(Brow + 16 * 256 + k);
        acc[0] = __builtin_amdgcn_mfma_f32_16x16x32_f16(af, b0, acc[0], 0, 0, 0);
        acc[1] = __builtin_amdgcn_mfma_f32_16x16x32_f16(af, b1, acc[1], 0, 0, 0);
    }
    #pragma unroll
    for (int nt = 0; nt < 2; nt++) {
        int n = nt * 16 + lr;
        float bias = b_out[n];
        #pragma unroll
        for (int i = 0; i < 4; i++) {
            int m = m0 + lq * 4 + i;
            logits[(size_t)m * KK + n] = acc[nt][i] + bias;
        }
    }
}

// ---------------------------------------------------------------- CRF forward + gold (one wave per sequence)
// R3: no barriers (single wave, in-order LDS); readlane-based rescale (tag 4 always live); ET row in VGPRs.
__global__ __launch_bounds__(64) void k_crf(const float* __restrict__ logits,
                                            const float* __restrict__ trans,
                                            const int* __restrict__ y,
                                            const int* __restrict__ lens,
                                            float* __restrict__ out) {
    int b = blockIdx.x;
    int lane = threadIdx.x;
    int k = lane & 31;
    __shared__ float TR[32][33];
    __shared__ __align__(16) float PS[32];

    for (int i = lane; i < 1024; i += 64) TR[i >> 5][i & 31] = trans[i];

    // ET row k in registers (both wave halves replicate)
    float et[32];
    const float* trow = trans + k * 32;
    #pragma unroll
    for (int j = 0; j < 32; j++) et[j] = __expf(trow[j]);   // exp(-10000) -> 0
    __syncthreads();

    int Lb = lens[b];
    const int* yb = y + b * (TT + 1);
    const float* lgb = logits + (size_t)(b * TT) * KK;

    // ---- gold score (parallel over t)
    float g = 0.f;
    for (int t = lane; t < Lb; t += 64) {
        int yt = yb[t], yt1 = yb[t + 1];
        g += lgb[(size_t)t * KK + yt1] + TR[yt1][yt];
    }
    #pragma unroll
    for (int s = 1; s < 64; s <<= 1) g += __shfl_xor(g, s);
    float gold = g + TR[3][yb[Lb]];   // + trans[EOS, last_tag]

    // ---- forward recursion; t=0 analytic (only SOS live)
    float score = lgb[k] + TR[k][2];

    for (int t = 1; t < Lb; t++) {
        float lg = lgb[(size_t)t * KK + k];
        // rescale by score[tag 4] (always live; live spread << 88)
        float m = __builtin_bit_cast(float, __builtin_amdgcn_readlane(__builtin_bit_cast(int, score), 4));
        float P = __expf(score - m);
        if (lane < 32) PS[k] = P;
        // wave-uniform broadcast reads; in-order LDS pipe makes write visible, no barrier
        float4 ps[8];
        #pragma unroll
        for (int j = 0; j < 8; j++) ps[j] = *(const float4*)&PS[j * 4];
        const float* psf = (const float*)ps;
        float a0 = 0.f, a1 = 0.f, a2 = 0.f, a3 = 0.f;
        #pragma unroll
        for (int j = 0; j < 8; j++) {
            a0 = fmaf(et[j], psf[j], a0);
            a1 = fmaf(et[j + 8], psf[j + 8], a1);
            a2 = fmaf(et[j + 16], psf[j + 16], a2);
            a3 = fmaf(et[j + 24], psf[j + 24], a3);
        }
        score = lg + m + __logf((a0 + a1) + (a2 + a3));
    }

    // logZ = LSE_k(score + trans[EOS,k]) (max-based, runs once)
    float v = score + TR[3][k];
    float m2 = v;
    #pragma unroll
    for (int s = 1; s < 32; s <<= 1) m2 = fmaxf(m2, __shfl_xor(m2, s));
    float e = __expf(v - m2);
    #pragma unroll
    for (int s = 1; s < 32; s <<= 1) e += __shfl_xor(e, s);
    float logZ = m2 + __logf(e);

    if (lane == 0) out[b] = logZ - gold;
}

// ----------------------------------------------------------------
extern "C" void kernel_launch(void* const* d_in, const int* in_sizes, int n_in,
                              void* d_out, int out_size, void* d_ws, size_t ws_size,
                              hipStream_t stream) {
    const int*   x      = (const int*)d_in[0];
    const int*   y      = (const int*)d_in[1];
    const float* embed  = (const float*)d_in[2];
    const float* wi_l0f = (const float*)d_in[3];
    const float* wh_l0f = (const float*)d_in[4];
    const float* b_l0f  = (const float*)d_in[5];
    const float* wi_l0b = (const float*)d_in[6];
    const float* wh_l0b = (const float*)d_in[7];
    const float* b_l0b  = (const float*)d_in[8];
    const float* wi_l1f = (const float*)d_in[9];
    const float* wh_l1f = (const float*)d_in[10];
    const float* b_l1f  = (const float*)d_in[11];
    const float* wi_l1b = (const float*)d_in[12];
    const float* wh_l1b = (const float*)d_in[13];
    const float* b_l1b  = (const float*)d_in[14];
    const float* w_out  = (const float*)d_in[15];
    const float* b_out  = (const float*)d_in[16];
    const float* trans  = (const float*)d_in[17];
    float* out = (float*)d_out;

    char* base = (char*)d_ws;
    size_t off = 0;
    auto take = [&](size_t bytes) -> char* {
        char* r = base + off;
        off = (off + bytes + 255) & ~(size_t)255;
        return r;
    };
    half_t* zA  = (half_t*)take((size_t)MTOT * NWID * 2);  // 64 MiB (reused layer0/layer1)
    half_t* h0  = (half_t*)take((size_t)MTOT * 256 * 2);   // 16 MiB
    half_t* h1  = (half_t*)take((size_t)MTOT * 256 * 2);   // 16 MiB
    half_t* e16 = (half_t*)take((size_t)MTOT * EE * 2);    // 8 MiB
    float*  lg  = (float*)take((size_t)MTOT * KK * 4);     // 4 MiB
    half_t* W0  = (half_t*)take((size_t)NWID * EE * 2);
    half_t* W1  = (half_t*)take((size_t)NWID * 256 * 2);
    half_t* WO  = (half_t*)take((size_t)KK * 256 * 2);
    int*    lens = (int*)take(BB * 4);

    k_lengths<<<BB, 256, 0, stream>>>(x, lens);
    k_pack<<<256, 256, 0, stream>>>(wi_l0f, wi_l0b, wi_l1f, wi_l1b, w_out, W0, W1, WO);
    k_embed<<<MTOT / 16, 256, 0, stream>>>(x, embed, e16);
    k_gemm<<<dim3(MTOT / 64, 4), 256, 0, stream>>>(e16, W0, b_l0f, b_l0b, zA, 128);
    k_lstm<<<BB * 2, 512, 0, stream>>>(zA, wh_l0f, wh_l0b, lens, h0);
    k_gemm<<<dim3(MTOT / 64, 4), 256, 0, stream>>>(h0, W1, b_l1f, b_l1b, zA, 256);
    k_lstm<<<BB * 2, 512, 0, stream>>>(zA, wh_l1f, wh_l1b, lens, h1);
    k_logits<<<MTOT / 64, 256, 0, stream>>>(h1, WO, b_out, lg);
    k_crf<<<BB, 64, 0, stream>>>(lg, trans, y, lens, out);
}